// Round 4
// baseline (10488.524 us; speedup 1.0000x reference)
//
#include <hip/hip_runtime.h>

// ---- problem dims ----
#define NN 20000
#define NE 640000
#define FF 128
#define H1 64
#define H2 32
#define RR 65
#define BQ 4096
#define NR (NN*RR)

// ---- small scratch block offsets (ints within sm[1024]) ----
#define SM_HIST_A 0
#define SM_START_A 128
#define SM_CUR_A 256
#define SM_HIST_B 384
#define SM_START_B 512
#define SM_CUR_B 640
#define SM_HACC 768   // 32 floats
#define SM_V 832      // 32 floats

#define CPB1 20       // blocks per relation, layer 1 (65*20=1300 ~ 5/CU, LDS-capped)
#define CPB2 32       // layer 2 (65*32=2080 ~ 8/CU)

// ===================== histogram: cnt[(dst,rel)] + per-type counts =====================
__global__ __launch_bounds__(256) void k_hist(
    const int* __restrict__ ei, const int* __restrict__ etA, const int* __restrict__ etB,
    int* __restrict__ cntA, int* __restrict__ cntB, int* __restrict__ sm) {
  __shared__ int lh[2 * RR];
  int tid = threadIdx.x;
  for (int i = tid; i < 2 * RR; i += blockDim.x) lh[i] = 0;
  __syncthreads();
  int e = blockIdx.x * blockDim.x + tid;
  if (e < NE) {
    int dst = ei[NE + e];
    int ta = etA[e], tb = etB[e];
    atomicAdd(&cntA[dst * RR + ta], 1);
    atomicAdd(&cntB[dst * RR + tb], 1);
    atomicAdd(&lh[ta], 1);
    atomicAdd(&lh[RR + tb], 1);
  }
  __syncthreads();
  for (int i = tid; i < 2 * RR; i += blockDim.x) {
    int c = lh[i];
    if (c) atomicAdd(&sm[(i < RR) ? (SM_HIST_A + i) : (SM_HIST_B + (i - RR))], c);
  }
}

// ===================== exclusive prefix over 65 bins =====================
__global__ __launch_bounds__(128) void k_prefix(int* __restrict__ sm) {
  int w = threadIdx.x >> 6;
  if ((threadIdx.x & 63) == 0 && w < 2) {
    int hb = w ? SM_HIST_B : SM_HIST_A;
    int sb = w ? SM_START_B : SM_START_A;
    int cb = w ? SM_CUR_B : SM_CUR_A;
    int h[RR];
#pragma unroll
    for (int r = 0; r < RR; ++r) h[r] = sm[hb + r];
    int s = 0;
#pragma unroll
    for (int r = 0; r < RR; ++r) { sm[sb + r] = s; sm[cb + r] = s; s += h[r]; }
  }
}

// ===================== counting-sort scatter =====================
__global__ __launch_bounds__(256) void k_scatter(
    const int* __restrict__ etA, const int* __restrict__ etB,
    int* __restrict__ sm, int* __restrict__ ordA, int* __restrict__ ordB) {
  __shared__ int lhA[RR], lbA[RR], lhB[RR], lbB[RR];
  int tid = threadIdx.x;
  for (int i = tid; i < RR; i += blockDim.x) { lhA[i] = 0; lhB[i] = 0; }
  __syncthreads();
  int e = blockIdx.x * blockDim.x + tid;
  int ta = 0, tb = 0, ra = 0, rb = 0;
  bool valid = (e < NE);
  if (valid) {
    ta = etA[e]; tb = etB[e];
    ra = atomicAdd(&lhA[ta], 1);
    rb = atomicAdd(&lhB[tb], 1);
  }
  __syncthreads();
  for (int i = tid; i < RR; i += blockDim.x) {
    if (lhA[i]) lbA[i] = atomicAdd(&sm[SM_CUR_A + i], lhA[i]);
    if (lhB[i]) lbB[i] = atomicAdd(&sm[SM_CUR_B + i], lhB[i]);
  }
  __syncthreads();
  if (valid) { ordA[lbA[ta] + ra] = e; ordB[lbB[tb] + rb] = e; }
}

// ===================== counts -> 1/cnt (float, in place) =====================
__global__ __launch_bounds__(256) void k_inv(int* __restrict__ cntA, int* __restrict__ cntB) {
  int i = blockIdx.x * blockDim.x + threadIdx.x;
  if (i < NR) {
    int c = cntA[i]; ((float*)cntA)[i] = (c > 0) ? 1.0f / (float)c : 0.0f;
    c = cntB[i];     ((float*)cntB)[i] = (c > 0) ? 1.0f / (float)c : 0.0f;
  }
}

// ===================== layer-1 root term =====================
__global__ __launch_bounds__(256) void k_root1(
    const float* __restrict__ xo, const float* __restrict__ xa,
    const float* __restrict__ rt, const float* __restrict__ b,
    float* __restrict__ yo, float* __restrict__ yaa, float* __restrict__ ya) {
  int lane = threadIdx.x & 63;
  int n = (blockIdx.x * blockDim.x + threadIdx.x) >> 6;
  if (n >= NN) return;
  const float4* xo4 = (const float4*)(xo + (size_t)n * FF);
  const float4* xa4 = (const float4*)(xa + (size_t)n * FF);
  float so = b[lane], sa = so;
#pragma unroll
  for (int j = 0; j < FF / 4; ++j) {
    float vo[4], va[4];
    *(float4*)vo = xo4[j];
    *(float4*)va = xa4[j];
#pragma unroll
    for (int t = 0; t < 4; ++t) {
      float wv = rt[(4 * j + t) * H1 + lane];
      so = fmaf(vo[t], wv, so);
      sa = fmaf(va[t], wv, sa);
    }
  }
  yo[(size_t)n * H1 + lane] = so;
  yaa[(size_t)n * H1 + lane] = so;
  ya[(size_t)n * H1 + lane] = sa;
}

// ===================== layer-1 edge transform+scatter ===============================
// W_r^T staged in LDS [o=64][k=128], 16B-chunk XOR-swizzled (chunk ^= o&31):
// lane's ds_read_b128 of its column is bank-conflict-free. x-rows and edge
// metadata via plain VMEM loads (vmcnt pipe) — uniform-address lanes coalesce
// to one L2 request, and vmcnt is decoupled from the ds_read lgkmcnt waits
// (round-3 lesson: s_load shares lgkmcnt with ds_read and serializes).
template <int NIN, int EPG>
__global__ __launch_bounds__(256, 4) void k_edge1(
    const int* __restrict__ ei, const int* __restrict__ ord,
    const int* __restrict__ sm, int startOff, int histOff,
    const float* __restrict__ invc, const float* __restrict__ W1,
    const float* __restrict__ xA, const float* __restrict__ xB,
    float* __restrict__ yA, float* __restrict__ yB) {
  __shared__ float wlds[FF * H1];          // 32 KB
  const int r = blockIdx.x / CPB1;
  {
    const int o = threadIdx.x & 63;
    const int kb = (threadIdx.x >> 6) << 5;
    const float* Wr = W1 + (size_t)r * (FF * H1);
#pragma unroll
    for (int j = 0; j < 32; ++j) {
      const int k = kb + j;
      const int sc = (k >> 2) ^ (o & 31);
      wlds[o * 128 + sc * 4 + (k & 3)] = Wr[(size_t)k * H1 + o];
    }
  }
  __syncthreads();
  const int lane = threadIdx.x & 63;       // = output column
  const int lx = lane & 31;
  const float* wrow = wlds + lane * 128;
  const int wvid = (blockIdx.x - r * CPB1) * 4 + (threadIdx.x >> 6);
  const int stride = CPB1 * 4;
  const int s0 = __builtin_amdgcn_readfirstlane(sm[startOff + r]);
  const int cnt = __builtin_amdgcn_readfirstlane(sm[histOff + r]);
  const int ngroups = (cnt + EPG - 1) / EPG;

  for (int G = wvid; G < ngroups; G += stride) {
    const int base = s0 + G * EPG;
    const int lim = cnt - G * EPG;
    int dst[EPG];
    float inv[EPG];
    const float* pA[EPG];
    const float* pB[EPG];
#pragma unroll
    for (int i = 0; i < EPG; ++i) {
      const int pi = (i < lim) ? i : 0;
      const int e = ord[base + pi];
      const int s = ei[e];
      dst[i] = ei[NE + e];
      const float iv = invc[(size_t)dst[i] * RR + r];
      inv[i] = (i < lim) ? iv : 0.f;
      pA[i] = xA + (size_t)s * FF;
      if constexpr (NIN == 2) pB[i] = xB + (size_t)s * FF;
    }
    float aA[EPG], aB[EPG];
#pragma unroll
    for (int i = 0; i < EPG; ++i) { aA[i] = 0.f; aB[i] = 0.f; }
#pragma unroll
    for (int c = 0; c < FF / 4; ++c) {
      const float4 w4 = *(const float4*)(wrow + ((c ^ lx) << 2));
      float xvA[EPG][4], xvB[EPG][4];
#pragma unroll
      for (int i = 0; i < EPG; ++i) {
        *(float4*)xvA[i] = *(const float4*)(pA[i] + (c << 2));
        if constexpr (NIN == 2) *(float4*)xvB[i] = *(const float4*)(pB[i] + (c << 2));
      }
#pragma unroll
      for (int i = 0; i < EPG; ++i) {
        aA[i] = fmaf(xvA[i][0], w4.x, aA[i]);
        aA[i] = fmaf(xvA[i][1], w4.y, aA[i]);
        aA[i] = fmaf(xvA[i][2], w4.z, aA[i]);
        aA[i] = fmaf(xvA[i][3], w4.w, aA[i]);
        if constexpr (NIN == 2) {
          aB[i] = fmaf(xvB[i][0], w4.x, aB[i]);
          aB[i] = fmaf(xvB[i][1], w4.y, aB[i]);
          aB[i] = fmaf(xvB[i][2], w4.z, aB[i]);
          aB[i] = fmaf(xvB[i][3], w4.w, aB[i]);
        }
      }
    }
#pragma unroll
    for (int i = 0; i < EPG; ++i) {
      unsafeAtomicAdd(&yA[(size_t)dst[i] * H1 + lane], aA[i] * inv[i]);
      if constexpr (NIN == 2)
        unsafeAtomicAdd(&yB[(size_t)dst[i] * H1 + lane], aB[i] * inv[i]);
    }
  }
}

// ===================== relu over contiguous x1 buffers =====================
__global__ __launch_bounds__(256) void k_relu4(float4* __restrict__ a, int n4) {
  int i = blockIdx.x * blockDim.x + threadIdx.x;
  if (i < n4) {
    float4 v = a[i];
    v.x = fmaxf(v.x, 0.f); v.y = fmaxf(v.y, 0.f);
    v.z = fmaxf(v.z, 0.f); v.w = fmaxf(v.w, 0.f);
    a[i] = v;
  }
}

// ===================== layer-2 root term =====================
__global__ __launch_bounds__(256) void k_root2(
    const float* __restrict__ x1, const float* __restrict__ rt,
    const float* __restrict__ b, float* __restrict__ y) {
  int i = blockIdx.x * blockDim.x + threadIdx.x;
  if (i >= NN * H2) return;
  int o = i & (H2 - 1);
  int n = i >> 5;
  const float4* x4 = (const float4*)(x1 + (size_t)n * H1);
  float s = b[o];
#pragma unroll
  for (int j = 0; j < H1 / 4; ++j) {
    float v[4];
    *(float4*)v = x4[j];
#pragma unroll
    for (int t = 0; t < 4; ++t) s = fmaf(v[t], rt[(4 * j + t) * H2 + o], s);
  }
  y[i] = s;
}

// ===================== layer-2 edge transform+scatter ===============================
// All 64 lanes redundantly compute o = lane&31 for EPG edges (x via uniform VMEM);
// wave halves split the atomic writes over edge pairs (i, i+EPG/2).
template <int NIN, int EPG>
__global__ __launch_bounds__(256, 4) void k_edge2(
    const int* __restrict__ ei, const int* __restrict__ ord,
    const int* __restrict__ sm, int startOff, int histOff,
    const float* __restrict__ invc, const float* __restrict__ W2,
    const float* __restrict__ xA, const float* __restrict__ xB,
    float* __restrict__ yA, float* __restrict__ yB) {
  __shared__ float wlds[H1 * H2];          // 8 KB, [o=32][k=64], chunk ^= o&15
  const int r = blockIdx.x / CPB2;
  {
    const int o = threadIdx.x & 31;
    const int kb = (threadIdx.x >> 5) << 3;
    const float* Wr = W2 + (size_t)r * (H1 * H2);
#pragma unroll
    for (int j = 0; j < 8; ++j) {
      const int k = kb + j;
      const int sc = (k >> 2) ^ (o & 15);
      wlds[o * 64 + sc * 4 + (k & 3)] = Wr[(size_t)k * H2 + o];
    }
  }
  __syncthreads();
  const int lane = threadIdx.x & 63;
  const int o = lane & 31;
  const int eh = lane >> 5;
  const int ox = o & 15;
  const float* wrow = wlds + o * 64;
  const int wvid = (blockIdx.x - r * CPB2) * 4 + (threadIdx.x >> 6);
  const int stride = CPB2 * 4;
  const int s0 = __builtin_amdgcn_readfirstlane(sm[startOff + r]);
  const int cnt = __builtin_amdgcn_readfirstlane(sm[histOff + r]);
  const int ngroups = (cnt + EPG - 1) / EPG;

  for (int G = wvid; G < ngroups; G += stride) {
    const int base = s0 + G * EPG;
    const int lim = cnt - G * EPG;
    int dst[EPG];
    float inv[EPG];
    const float* pA[EPG];
    const float* pB[EPG];
#pragma unroll
    for (int i = 0; i < EPG; ++i) {
      const int pi = (i < lim) ? i : 0;
      const int e = ord[base + pi];
      const int s = ei[e];
      dst[i] = ei[NE + e];
      const float iv = invc[(size_t)dst[i] * RR + r];
      inv[i] = (i < lim) ? iv : 0.f;
      pA[i] = xA + (size_t)s * H1;
      if constexpr (NIN == 2) pB[i] = xB + (size_t)s * H1;
    }
    float aA[EPG], aB[EPG];
#pragma unroll
    for (int i = 0; i < EPG; ++i) { aA[i] = 0.f; aB[i] = 0.f; }
#pragma unroll
    for (int c = 0; c < H1 / 4; ++c) {
      const float4 w4 = *(const float4*)(wrow + ((c ^ ox) << 2));
      float xvA[EPG][4], xvB[EPG][4];
#pragma unroll
      for (int i = 0; i < EPG; ++i) {
        *(float4*)xvA[i] = *(const float4*)(pA[i] + (c << 2));
        if constexpr (NIN == 2) *(float4*)xvB[i] = *(const float4*)(pB[i] + (c << 2));
      }
#pragma unroll
      for (int i = 0; i < EPG; ++i) {
        aA[i] = fmaf(xvA[i][0], w4.x, aA[i]);
        aA[i] = fmaf(xvA[i][1], w4.y, aA[i]);
        aA[i] = fmaf(xvA[i][2], w4.z, aA[i]);
        aA[i] = fmaf(xvA[i][3], w4.w, aA[i]);
        if constexpr (NIN == 2) {
          aB[i] = fmaf(xvB[i][0], w4.x, aB[i]);
          aB[i] = fmaf(xvB[i][1], w4.y, aB[i]);
          aB[i] = fmaf(xvB[i][2], w4.z, aB[i]);
          aB[i] = fmaf(xvB[i][3], w4.w, aB[i]);
        }
      }
    }
#pragma unroll
    for (int i = 0; i < EPG / 2; ++i) {
      const int j = i + EPG / 2;
      const int dsel = eh ? dst[j] : dst[i];
      const float vA = eh ? aA[j] * inv[j] : aA[i] * inv[i];
      unsafeAtomicAdd(&yA[(size_t)dsel * H2 + o], vA);
      if constexpr (NIN == 2) {
        const float vB = eh ? aB[j] * inv[j] : aB[i] * inv[i];
        unsafeAtomicAdd(&yB[(size_t)dsel * H2 + o], vB);
      }
    }
  }
}

// ===================== column sum of x2_o -> hacc[32] =====================
__global__ __launch_bounds__(256) void k_colsum(const float* __restrict__ x2o,
                                                float* __restrict__ hacc) {
  int tid = threadIdx.x;
  int col = tid & 31;
  int rgrp = blockIdx.x * (blockDim.x >> 5) + (tid >> 5);
  int nth = gridDim.x * (blockDim.x >> 5);
  float s = 0.f;
  for (int n = rgrp; n < NN; n += nth) s += x2o[(size_t)n * H2 + col];
  unsafeAtomicAdd(&hacc[col], s);
}

// ===================== h_os = sigmoid(mean); v = disc_w @ h_os =====================
__global__ __launch_bounds__(64) void k_disc(const float* __restrict__ hacc,
                                             const float* __restrict__ dw,
                                             float* __restrict__ vout) {
  __shared__ float hos[H2];
  int t = threadIdx.x;
  if (t < H2) hos[t] = 1.0f / (1.0f + expf(-hacc[t] / (float)NN));
  __syncthreads();
  if (t < H2) {
    float s = 0.f;
#pragma unroll
    for (int k = 0; k < H2; ++k) s = fmaf(dw[t * H2 + k], hos[k], s);
    vout[t] = s;
  }
}

// ===================== ret_os / ret_os_a (col0 shared) =====================
__global__ __launch_bounds__(256) void k_ret(
    const float* __restrict__ x2o, const float* __restrict__ x2oa, const float* __restrict__ x2oaa,
    const float* __restrict__ v, const float* __restrict__ db,
    float* __restrict__ ros, float* __restrict__ rosa) {
  int n = blockIdx.x * blockDim.x + threadIdx.x;
  if (n >= NN) return;
  const float4* a4 = (const float4*)(x2o + (size_t)n * H2);
  const float4* b4 = (const float4*)(x2oa + (size_t)n * H2);
  const float4* c4 = (const float4*)(x2oaa + (size_t)n * H2);
  const float4* v4 = (const float4*)v;
  float r0 = 0.f, r1 = 0.f, r2 = 0.f;
#pragma unroll
  for (int j = 0; j < H2 / 4; ++j) {
    float va[4], vb[4], vc[4], vv[4];
    *(float4*)va = a4[j]; *(float4*)vb = b4[j]; *(float4*)vc = c4[j]; *(float4*)vv = v4[j];
#pragma unroll
    for (int t = 0; t < 4; ++t) {
      r0 = fmaf(va[t], vv[t], r0);
      r1 = fmaf(vb[t], vv[t], r1);
      r2 = fmaf(vc[t], vv[t], r2);
    }
  }
  float bb = db[0];
  ros[n * 2] = r0 + bb;  ros[n * 2 + 1] = r1 + bb;
  rosa[n * 2] = r0 + bb; rosa[n * 2 + 1] = r2 + bb;
}

// ===================== classifier: log[b][r] =====================
__global__ __launch_bounds__(128) void k_cls(
    const int* __restrict__ idx, const float* __restrict__ x1o, const float* __restrict__ x2o,
    const float* __restrict__ attt, const float* __restrict__ cw, const float* __restrict__ cb,
    float* __restrict__ lg) {
  int b = blockIdx.x;
  int r = threadIdx.x;
  if (r >= RR) return;
  int i1 = idx[b], i2 = idx[BQ + b];
  float a0 = attt[0], a1 = attt[1];
  float acc = cb[r];
  const float4* q1 = (const float4*)(x1o + (size_t)i1 * H1);
  const float4* q2 = (const float4*)(x2o + (size_t)i1 * H2);
  const float4* q3 = (const float4*)(x1o + (size_t)i2 * H1);
  const float4* q4 = (const float4*)(x2o + (size_t)i2 * H2);
#pragma unroll
  for (int j = 0; j < H1 / 4; ++j) {
    float v[4]; *(float4*)v = q1[j];
#pragma unroll
    for (int t = 0; t < 4; ++t) acc = fmaf(a0 * v[t], cw[(4 * j + t) * RR + r], acc);
  }
#pragma unroll
  for (int j = 0; j < H2 / 4; ++j) {
    float v[4]; *(float4*)v = q2[j];
#pragma unroll
    for (int t = 0; t < 4; ++t) acc = fmaf(a1 * v[t], cw[(H1 + 4 * j + t) * RR + r], acc);
  }
#pragma unroll
  for (int j = 0; j < H1 / 4; ++j) {
    float v[4]; *(float4*)v = q3[j];
#pragma unroll
    for (int t = 0; t < 4; ++t) acc = fmaf(a0 * v[t], cw[(96 + 4 * j + t) * RR + r], acc);
  }
#pragma unroll
  for (int j = 0; j < H2 / 4; ++j) {
    float v[4]; *(float4*)v = q4[j];
#pragma unroll
    for (int t = 0; t < 4; ++t) acc = fmaf(a1 * v[t], cw[(96 + H1 + 4 * j + t) * RR + r], acc);
  }
  lg[(size_t)b * RR + r] = acc;
}

// ===================== launch =====================
extern "C" void kernel_launch(void* const* d_in, const int* in_sizes, int n_in,
                              void* d_out, int out_size, void* d_ws, size_t ws_size,
                              hipStream_t stream) {
  const float* x_o  = (const float*)d_in[0];
  const float* x_a  = (const float*)d_in[1];
  const int*   ei   = (const int*)d_in[2];
  const int*   etA  = (const int*)d_in[3];
  const int*   etB  = (const int*)d_in[4];
  const int*   idx  = (const int*)d_in[5];
  const float* W1   = (const float*)d_in[6];
  const float* rt1  = (const float*)d_in[7];
  const float* b1   = (const float*)d_in[8];
  const float* W2   = (const float*)d_in[9];
  const float* rt2  = (const float*)d_in[10];
  const float* b2   = (const float*)d_in[11];
  const float* attt = (const float*)d_in[12];
  const float* dw   = (const float*)d_in[13];
  const float* db   = (const float*)d_in[14];
  const float* cw   = (const float*)d_in[15];
  const float* cb   = (const float*)d_in[16];

  const size_t NRp = 1300224;
  int* wsI  = (int*)d_ws;
  int* cntA = wsI;
  int* cntB = wsI + NRp;
  int* sm   = wsI + 2 * NRp;
  int* ordA = sm + 1024;
  int* ordB = ordA + NE;
  float* x1o   = (float*)(ordB + NE);
  float* x1a   = x1o + (size_t)NN * H1;
  float* x1aa  = x1a + (size_t)NN * H1;
  float* x2oa  = x1aa + (size_t)NN * H1;
  float* x2oaa = x2oa + (size_t)NN * H2;
  float* smF   = (float*)sm;
  float* hacc  = smF + SM_HACC;
  float* vbuf  = smF + SM_V;

  float* outF   = (float*)d_out;
  float* o_log  = outF;
  float* o_ros  = outF + (size_t)BQ * RR;
  float* o_rosa = o_ros + (size_t)NN * 2;
  float* o_x2o  = o_rosa + (size_t)NN * 2;

  hipMemsetAsync(wsI, 0, (2 * NRp + 1024) * sizeof(int), stream);

  k_hist<<<(NE + 255) / 256, 256, 0, stream>>>(ei, etA, etB, cntA, cntB, sm);
  k_prefix<<<1, 128, 0, stream>>>(sm);
  k_scatter<<<(NE + 255) / 256, 256, 0, stream>>>(etA, etB, sm, ordA, ordB);
  k_inv<<<(NR + 255) / 256, 256, 0, stream>>>(cntA, cntB);

  k_root1<<<(NN * H1) / 256, 256, 0, stream>>>(x_o, x_a, rt1, b1, x1o, x1aa, x1a);
  k_edge1<2, 4><<<RR * CPB1, 256, 0, stream>>>(ei, ordA, sm, SM_START_A, SM_HIST_A,
                                               (const float*)cntA, W1, x_o, x_a, x1o, x1a);
  k_edge1<1, 8><<<RR * CPB1, 256, 0, stream>>>(ei, ordB, sm, SM_START_B, SM_HIST_B,
                                               (const float*)cntB, W1, x_o, nullptr, x1aa, nullptr);
  k_relu4<<<(3 * NN * H1 / 4 + 255) / 256, 256, 0, stream>>>((float4*)x1o, 3 * NN * H1 / 4);

  k_root2<<<(NN * H2 + 255) / 256, 256, 0, stream>>>(x1o, rt2, b2, o_x2o);
  k_root2<<<(NN * H2 + 255) / 256, 256, 0, stream>>>(x1a, rt2, b2, x2oa);
  k_root2<<<(NN * H2 + 255) / 256, 256, 0, stream>>>(x1aa, rt2, b2, x2oaa);
  k_edge2<2, 8><<<RR * CPB2, 256, 0, stream>>>(ei, ordA, sm, SM_START_A, SM_HIST_A,
                                               (const float*)cntA, W2, x1o, x1a, o_x2o, x2oa);
  k_edge2<1, 8><<<RR * CPB2, 256, 0, stream>>>(ei, ordB, sm, SM_START_B, SM_HIST_B,
                                               (const float*)cntB, W2, x1aa, nullptr, x2oaa, nullptr);

  k_colsum<<<128, 256, 0, stream>>>(o_x2o, hacc);
  k_disc<<<1, 64, 0, stream>>>(hacc, dw, vbuf);
  k_ret<<<(NN + 255) / 256, 256, 0, stream>>>(o_x2o, x2oa, x2oaa, vbuf, db, o_ros, o_rosa);
  k_cls<<<BQ, 128, 0, stream>>>(idx, x1o, o_x2o, attt, cw, cb, o_log);
}

// Round 5
// 2336.596 us; speedup vs baseline: 4.4888x; 4.4888x over previous
//
#include <hip/hip_runtime.h>

// ---- problem dims ----
#define NN 20000
#define NE 640000
#define FF 128
#define H1 64
#define H2 32
#define RR 65
#define BQ 4096
#define NR (NN*RR)

// ---- small scratch block offsets (ints within sm[1024]) ----
#define SM_HIST_A 0
#define SM_START_A 128
#define SM_CUR_A 256
#define SM_HIST_B 384
#define SM_START_B 512
#define SM_CUR_B 640
#define SM_HACC 768   // 32 floats
#define SM_V 832      // 32 floats

#define CPB1 8        // blocks/relation, layer 1: 520 blocks ~ 2/CU (64KB LDS each)
#define CPB2 16       // layer 2: 1040 blocks ~ 4/CU (24KB LDS each)

// ===================== histogram =====================
__global__ __launch_bounds__(256) void k_hist(
    const int* __restrict__ ei, const int* __restrict__ etA, const int* __restrict__ etB,
    int* __restrict__ cntA, int* __restrict__ cntB, int* __restrict__ sm) {
  __shared__ int lh[2 * RR];
  int tid = threadIdx.x;
  for (int i = tid; i < 2 * RR; i += blockDim.x) lh[i] = 0;
  __syncthreads();
  int e = blockIdx.x * blockDim.x + tid;
  if (e < NE) {
    int dst = ei[NE + e];
    int ta = etA[e], tb = etB[e];
    atomicAdd(&cntA[dst * RR + ta], 1);
    atomicAdd(&cntB[dst * RR + tb], 1);
    atomicAdd(&lh[ta], 1);
    atomicAdd(&lh[RR + tb], 1);
  }
  __syncthreads();
  for (int i = tid; i < 2 * RR; i += blockDim.x) {
    int c = lh[i];
    if (c) atomicAdd(&sm[(i < RR) ? (SM_HIST_A + i) : (SM_HIST_B + (i - RR))], c);
  }
}

// ===================== exclusive prefix over 65 bins =====================
__global__ __launch_bounds__(128) void k_prefix(int* __restrict__ sm) {
  int w = threadIdx.x >> 6;
  if ((threadIdx.x & 63) == 0 && w < 2) {
    int hb = w ? SM_HIST_B : SM_HIST_A;
    int sb = w ? SM_START_B : SM_START_A;
    int cb = w ? SM_CUR_B : SM_CUR_A;
    int h[RR];
#pragma unroll
    for (int r = 0; r < RR; ++r) h[r] = sm[hb + r];
    int s = 0;
#pragma unroll
    for (int r = 0; r < RR; ++r) { sm[sb + r] = s; sm[cb + r] = s; s += h[r]; }
  }
}

// ===================== counting-sort scatter =====================
__global__ __launch_bounds__(256) void k_scatter(
    const int* __restrict__ etA, const int* __restrict__ etB,
    int* __restrict__ sm, int* __restrict__ ordA, int* __restrict__ ordB) {
  __shared__ int lhA[RR], lbA[RR], lhB[RR], lbB[RR];
  int tid = threadIdx.x;
  for (int i = tid; i < RR; i += blockDim.x) { lhA[i] = 0; lhB[i] = 0; }
  __syncthreads();
  int e = blockIdx.x * blockDim.x + tid;
  int ta = 0, tb = 0, ra = 0, rb = 0;
  bool valid = (e < NE);
  if (valid) {
    ta = etA[e]; tb = etB[e];
    ra = atomicAdd(&lhA[ta], 1);
    rb = atomicAdd(&lhB[tb], 1);
  }
  __syncthreads();
  for (int i = tid; i < RR; i += blockDim.x) {
    if (lhA[i]) lbA[i] = atomicAdd(&sm[SM_CUR_A + i], lhA[i]);
    if (lhB[i]) lbB[i] = atomicAdd(&sm[SM_CUR_B + i], lhB[i]);
  }
  __syncthreads();
  if (valid) { ordA[lbA[ta] + ra] = e; ordB[lbB[tb] + rb] = e; }
}

// ===================== counts -> 1/cnt =====================
__global__ __launch_bounds__(256) void k_inv(int* __restrict__ cntA, int* __restrict__ cntB) {
  int i = blockIdx.x * blockDim.x + threadIdx.x;
  if (i < NR) {
    int c = cntA[i]; ((float*)cntA)[i] = (c > 0) ? 1.0f / (float)c : 0.0f;
    c = cntB[i];     ((float*)cntB)[i] = (c > 0) ? 1.0f / (float)c : 0.0f;
  }
}

// ===================== flatten per-position edge meta: (src,dst) + inv ============
// Kills the ord->ei->invc dependent-load chain inside the edge kernels.
__global__ __launch_bounds__(256) void k_emeta(
    const int* __restrict__ ei, const int* __restrict__ ordA, const int* __restrict__ ordB,
    const float* __restrict__ invA, const float* __restrict__ invB,
    const int* __restrict__ etA, const int* __restrict__ etB,
    int2* __restrict__ sdA, float* __restrict__ ivA,
    int2* __restrict__ sdB, float* __restrict__ ivB) {
  int p = blockIdx.x * blockDim.x + threadIdx.x;
  if (p >= NE) return;
  {
    int e = ordA[p]; int s = ei[e], d = ei[NE + e]; int t = etA[e];
    sdA[p] = make_int2(s, d); ivA[p] = invA[(size_t)d * RR + t];
  }
  {
    int e = ordB[p]; int s = ei[e], d = ei[NE + e]; int t = etB[e];
    sdB[p] = make_int2(s, d); ivB[p] = invB[(size_t)d * RR + t];
  }
}

// ===================== layer-1 root term =====================
__global__ __launch_bounds__(256) void k_root1(
    const float* __restrict__ xo, const float* __restrict__ xa,
    const float* __restrict__ rt, const float* __restrict__ b,
    float* __restrict__ yo, float* __restrict__ yaa, float* __restrict__ ya) {
  int lane = threadIdx.x & 63;
  int n = (blockIdx.x * blockDim.x + threadIdx.x) >> 6;
  if (n >= NN) return;
  const float4* xo4 = (const float4*)(xo + (size_t)n * FF);
  const float4* xa4 = (const float4*)(xa + (size_t)n * FF);
  float so = b[lane], sa = so;
#pragma unroll
  for (int j = 0; j < FF / 4; ++j) {
    float vo[4], va[4];
    *(float4*)vo = xo4[j];
    *(float4*)va = xa4[j];
#pragma unroll
    for (int t = 0; t < 4; ++t) {
      float wv = rt[(4 * j + t) * H1 + lane];
      so = fmaf(vo[t], wv, so);
      sa = fmaf(va[t], wv, sa);
    }
  }
  yo[(size_t)n * H1 + lane] = so;
  yaa[(size_t)n * H1 + lane] = so;
  ya[(size_t)n * H1 + lane] = sa;
}

// ---- meta loader: single-level, fully-pipelineable loads (P always < ngroups) ----
#define LOADMETA(P, S, D, V)                                        \
  {                                                                 \
    const int lim_ = cnt - (P) * EPG;                               \
    const int gb_ = s0 + (P) * EPG;                                 \
    _Pragma("unroll")                                               \
    for (int i_ = 0; i_ < EPG; ++i_) {                              \
      const int off_ = gb_ + ((i_ < lim_) ? i_ : 0);                \
      const int2 sd_ = sdp[off_];                                   \
      S[i_] = sd_.x; D[i_] = sd_.y;                                 \
      const float iv_ = invp[off_];                                 \
      V[i_] = (i_ < lim_) ? iv_ : 0.f;                              \
    }                                                               \
  }

// ===================== layer-1 edge transform+scatter ===============================
// W_r^T in LDS [o=64][chunk ^ (o&31)] (proven r3/r4). x rows (8 per group) staged
// in wave-private LDS double-buffers via reg-staged vector loads; only one float4
// per staging instr lives in registers -> no spill. 2-deep pipeline: issue x(g+1)
// before compute(g), ds_write after (T14; compiler-placed waitcnts).
template <int NIN, int EPG>   // NIN*EPG == 8 rows/group
__global__ __launch_bounds__(256, 2) void k_edge1(
    const int2* __restrict__ sdp, const float* __restrict__ invp,
    const int* __restrict__ sm, int startOff, int histOff,
    const float* __restrict__ W1,
    const float* __restrict__ xA, const float* __restrict__ xB,
    float* __restrict__ yA, float* __restrict__ yB) {
  __shared__ __align__(16) float wlds[FF * H1];       // 32 KB
  __shared__ __align__(16) float xlds[4][2][8 * FF];  // 32 KB (4 waves x dbuf x 8 rows)
  const int r = blockIdx.x / CPB1;
  {
    const int o = threadIdx.x & 63;
    const int kb = (threadIdx.x >> 6) << 5;
    const float* Wr = W1 + (size_t)r * (FF * H1);
#pragma unroll
    for (int j = 0; j < 32; ++j) {
      const int k = kb + j;
      const int sc = (k >> 2) ^ (o & 31);
      wlds[o * 128 + sc * 4 + (k & 3)] = Wr[(size_t)k * H1 + o];
    }
  }
  __syncthreads();
  const int lane = threadIdx.x & 63;   // output column
  const int wid  = threadIdx.x >> 6;
  const int lx = lane & 31;
  const float* wrow = wlds + lane * 128;
  const int wvid = (blockIdx.x - r * CPB1) * 4 + wid;
  const int stride = CPB1 * 4;
  const int s0  = sm[startOff + r];
  const int cnt = sm[histOff + r];
  const int ngroups = (cnt + EPG - 1) / EPG;
  if (wvid >= ngroups) return;

// stage step s (0..3) covers LDS rows 2s (lanes 0-31) and 2s+1 (lanes 32-63)
#define XLOAD1(S, XR)                                                        \
  _Pragma("unroll")                                                          \
  for (int s_ = 0; s_ < 4; ++s_) {                                           \
    const float* bp_;                                                        \
    if constexpr (NIN == 2) {                                                \
      bp_ = (lane < 32 ? xA : xB) + (size_t)S[s_] * FF;                      \
    } else {                                                                 \
      bp_ = xA + (size_t)(lane < 32 ? S[2 * s_] : S[2 * s_ + 1]) * FF;       \
    }                                                                        \
    XR[s_] = *(const float4*)(bp_ + ((lane & 31) << 2));                     \
  }
#define XWRITE1(XR, BUFP)                                                    \
  _Pragma("unroll")                                                          \
  for (int s_ = 0; s_ < 4; ++s_) {                                           \
    *(float4*)((BUFP) + (2 * s_ + (lane >> 5)) * FF + ((lane & 31) << 2)) = XR[s_]; \
  }

  int srcC[EPG], dstC[EPG]; float invC[EPG];
  int srcN[EPG], dstN[EPG]; float invN[EPG];
  float4 xr[4];

  int G = wvid;
  LOADMETA(G, srcC, dstC, invC);
  {
    const int Pn = (G + stride < ngroups) ? (G + stride) : G;
    LOADMETA(Pn, srcN, dstN, invN);
  }
  XLOAD1(srcC, xr);
  XWRITE1(xr, &xlds[wid][0][0]);
  int buf = 0;

  for (; G < ngroups; G += stride) {
    const float* curp = &xlds[wid][buf][0];
    float* nxtp = &xlds[wid][buf ^ 1][0];
    XLOAD1(srcN, xr);                         // x for G+stride (meta arrived last iter)
    int srcN2[EPG], dstN2[EPG]; float invN2[EPG];
    {
      const int p1 = (G + stride < ngroups) ? (G + stride) : G;
      const int P2 = (G + 2 * stride < ngroups) ? (G + 2 * stride) : p1;
      LOADMETA(P2, srcN2, dstN2, invN2);
    }
    // compute group G
    float acc[8];
#pragma unroll
    for (int t = 0; t < 8; ++t) acc[t] = 0.f;
#pragma unroll 4
    for (int c = 0; c < 32; ++c) {
      const float4 w4 = *(const float4*)(wrow + ((c ^ lx) << 2));
#pragma unroll
      for (int t = 0; t < 8; ++t) {
        const float4 xv = *(const float4*)(curp + t * FF + (c << 2));
        acc[t] = fmaf(xv.x, w4.x, acc[t]);
        acc[t] = fmaf(xv.y, w4.y, acc[t]);
        acc[t] = fmaf(xv.z, w4.z, acc[t]);
        acc[t] = fmaf(xv.w, w4.w, acc[t]);
      }
    }
#pragma unroll
    for (int t = 0; t < 8; ++t) {
      if constexpr (NIN == 2) {
        float* yp = (t & 1) ? yB : yA;
        unsafeAtomicAdd(&yp[(size_t)dstC[t >> 1] * H1 + lane], acc[t] * invC[t >> 1]);
      } else {
        unsafeAtomicAdd(&yA[(size_t)dstC[t] * H1 + lane], acc[t] * invC[t]);
      }
    }
    XWRITE1(xr, nxtp);                        // loads issued pre-compute -> ready
#pragma unroll
    for (int i = 0; i < EPG; ++i) {
      srcC[i] = srcN[i]; dstC[i] = dstN[i]; invC[i] = invN[i];
      srcN[i] = srcN2[i]; dstN[i] = dstN2[i]; invN[i] = invN2[i];
    }
    buf ^= 1;
  }
#undef XLOAD1
#undef XWRITE1
}

// ===================== relu =====================
__global__ __launch_bounds__(256) void k_relu4(float4* __restrict__ a, int n4) {
  int i = blockIdx.x * blockDim.x + threadIdx.x;
  if (i < n4) {
    float4 v = a[i];
    v.x = fmaxf(v.x, 0.f); v.y = fmaxf(v.y, 0.f);
    v.z = fmaxf(v.z, 0.f); v.w = fmaxf(v.w, 0.f);
    a[i] = v;
  }
}

// ===================== layer-2 root term =====================
__global__ __launch_bounds__(256) void k_root2(
    const float* __restrict__ x1, const float* __restrict__ rt,
    const float* __restrict__ b, float* __restrict__ y) {
  int i = blockIdx.x * blockDim.x + threadIdx.x;
  if (i >= NN * H2) return;
  int o = i & (H2 - 1);
  int n = i >> 5;
  const float4* x4 = (const float4*)(x1 + (size_t)n * H1);
  float s = b[o];
#pragma unroll
  for (int j = 0; j < H1 / 4; ++j) {
    float v[4];
    *(float4*)v = x4[j];
#pragma unroll
    for (int t = 0; t < 4; ++t) s = fmaf(v[t], rt[(4 * j + t) * H2 + o], s);
  }
  y[i] = s;
}

// ===================== layer-2 edge transform+scatter ===============================
// Split-k: half = lane>>5 covers 32 of 64 k's; o = lane&31 output col; shfl_xor(32)
// combines. Same LDS x staging + 2-deep pipeline as k_edge1.
template <int NIN, int EPG>   // NIN*EPG == 8 rows/group
__global__ __launch_bounds__(256, 4) void k_edge2(
    const int2* __restrict__ sdp, const float* __restrict__ invp,
    const int* __restrict__ sm, int startOff, int histOff,
    const float* __restrict__ W2,
    const float* __restrict__ xA, const float* __restrict__ xB,
    float* __restrict__ yA, float* __restrict__ yB) {
  __shared__ __align__(16) float wlds[H1 * H2];       // 8 KB, [o=32][chunk ^ (o&15)]
  __shared__ __align__(16) float xlds[4][2][8 * H1];  // 16 KB
  const int r = blockIdx.x / CPB2;
  {
    const int o = threadIdx.x & 31;
    const int kb = (threadIdx.x >> 5) << 3;
    const float* Wr = W2 + (size_t)r * (H1 * H2);
#pragma unroll
    for (int j = 0; j < 8; ++j) {
      const int k = kb + j;
      const int sc = (k >> 2) ^ (o & 15);
      wlds[o * 64 + sc * 4 + (k & 3)] = Wr[(size_t)k * H2 + o];
    }
  }
  __syncthreads();
  const int lane = threadIdx.x & 63;
  const int wid  = threadIdx.x >> 6;
  const int o  = lane & 31;
  const int eh = lane >> 5;
  const int ox = o & 15;
  const float* wrow = wlds + o * 64;
  const int wvid = (blockIdx.x - r * CPB2) * 4 + wid;
  const int stride = CPB2 * 4;
  const int s0  = sm[startOff + r];
  const int cnt = sm[histOff + r];
  const int ngroups = (cnt + EPG - 1) / EPG;
  if (wvid >= ngroups) return;

// stage step s (0..1) covers LDS rows 4s+q, q = lane>>4 (16 lanes per 256B row)
#define XLOAD2(S, XR)                                                        \
  _Pragma("unroll")                                                          \
  for (int s_ = 0; s_ < 2; ++s_) {                                           \
    const int q_ = lane >> 4;                                                \
    const float* bp_;                                                        \
    if constexpr (NIN == 2) {                                                \
      const int e_ = (q_ >> 1) ? S[2 * s_ + 1] : S[2 * s_];                  \
      bp_ = ((q_ & 1) ? xB : xA) + (size_t)e_ * H1;                          \
    } else {                                                                 \
      const int e_ = (q_ == 0) ? S[4 * s_] : (q_ == 1) ? S[4 * s_ + 1]       \
                   : (q_ == 2) ? S[4 * s_ + 2] : S[4 * s_ + 3];              \
      bp_ = xA + (size_t)e_ * H1;                                            \
    }                                                                        \
    XR[s_] = *(const float4*)(bp_ + ((lane & 15) << 2));                     \
  }
#define XWRITE2(XR, BUFP)                                                    \
  _Pragma("unroll")                                                          \
  for (int s_ = 0; s_ < 2; ++s_) {                                           \
    *(float4*)((BUFP) + (4 * s_ + (lane >> 4)) * H1 + ((lane & 15) << 2)) = XR[s_]; \
  }

  int srcC[EPG], dstC[EPG]; float invC[EPG];
  int srcN[EPG], dstN[EPG]; float invN[EPG];
  float4 xr[2];

  int G = wvid;
  LOADMETA(G, srcC, dstC, invC);
  {
    const int Pn = (G + stride < ngroups) ? (G + stride) : G;
    LOADMETA(Pn, srcN, dstN, invN);
  }
  XLOAD2(srcC, xr);
  XWRITE2(xr, &xlds[wid][0][0]);
  int buf = 0;

  for (; G < ngroups; G += stride) {
    const float* curp = &xlds[wid][buf][0];
    float* nxtp = &xlds[wid][buf ^ 1][0];
    XLOAD2(srcN, xr);
    int srcN2[EPG], dstN2[EPG]; float invN2[EPG];
    {
      const int p1 = (G + stride < ngroups) ? (G + stride) : G;
      const int P2 = (G + 2 * stride < ngroups) ? (G + 2 * stride) : p1;
      LOADMETA(P2, srcN2, dstN2, invN2);
    }
    float acc[8];
#pragma unroll
    for (int t = 0; t < 8; ++t) acc[t] = 0.f;
#pragma unroll
    for (int c = 0; c < 8; ++c) {
      const int ch = (eh << 3) + c;                    // this half's k-chunk
      const float4 w4 = *(const float4*)(wrow + ((ch ^ ox) << 2));
#pragma unroll
      for (int t = 0; t < 8; ++t) {
        const float4 xv = *(const float4*)(curp + t * H1 + (ch << 2));
        acc[t] = fmaf(xv.x, w4.x, acc[t]);
        acc[t] = fmaf(xv.y, w4.y, acc[t]);
        acc[t] = fmaf(xv.z, w4.z, acc[t]);
        acc[t] = fmaf(xv.w, w4.w, acc[t]);
      }
    }
#pragma unroll
    for (int t = 0; t < 4; ++t) {
      float sa = acc[2 * t], sb = acc[2 * t + 1];
      sa += __shfl_xor(sa, 32);
      sb += __shfl_xor(sb, 32);
      if constexpr (NIN == 2) {
        const int d = dstC[t];
        const float vv = (eh ? sb : sa) * invC[t];
        float* yp = eh ? yB : yA;
        unsafeAtomicAdd(&yp[(size_t)d * H2 + o], vv);
      } else {
        const int d = eh ? dstC[2 * t + 1] : dstC[2 * t];
        const float vv = eh ? sb * invC[2 * t + 1] : sa * invC[2 * t];
        unsafeAtomicAdd(&yA[(size_t)d * H2 + o], vv);
      }
    }
    XWRITE2(xr, nxtp);
#pragma unroll
    for (int i = 0; i < EPG; ++i) {
      srcC[i] = srcN[i]; dstC[i] = dstN[i]; invC[i] = invN[i];
      srcN[i] = srcN2[i]; dstN[i] = dstN2[i]; invN[i] = invN2[i];
    }
    buf ^= 1;
  }
#undef XLOAD2
#undef XWRITE2
}

// ===================== column sum of x2_o -> hacc[32] =====================
__global__ __launch_bounds__(256) void k_colsum(const float* __restrict__ x2o,
                                                float* __restrict__ hacc) {
  int tid = threadIdx.x;
  int col = tid & 31;
  int rgrp = blockIdx.x * (blockDim.x >> 5) + (tid >> 5);
  int nth = gridDim.x * (blockDim.x >> 5);
  float s = 0.f;
  for (int n = rgrp; n < NN; n += nth) s += x2o[(size_t)n * H2 + col];
  unsafeAtomicAdd(&hacc[col], s);
}

// ===================== h_os = sigmoid(mean); v = disc_w @ h_os =====================
__global__ __launch_bounds__(64) void k_disc(const float* __restrict__ hacc,
                                             const float* __restrict__ dw,
                                             float* __restrict__ vout) {
  __shared__ float hos[H2];
  int t = threadIdx.x;
  if (t < H2) hos[t] = 1.0f / (1.0f + expf(-hacc[t] / (float)NN));
  __syncthreads();
  if (t < H2) {
    float s = 0.f;
#pragma unroll
    for (int k = 0; k < H2; ++k) s = fmaf(dw[t * H2 + k], hos[k], s);
    vout[t] = s;
  }
}

// ===================== ret_os / ret_os_a =====================
__global__ __launch_bounds__(256) void k_ret(
    const float* __restrict__ x2o, const float* __restrict__ x2oa, const float* __restrict__ x2oaa,
    const float* __restrict__ v, const float* __restrict__ db,
    float* __restrict__ ros, float* __restrict__ rosa) {
  int n = blockIdx.x * blockDim.x + threadIdx.x;
  if (n >= NN) return;
  const float4* a4 = (const float4*)(x2o + (size_t)n * H2);
  const float4* b4 = (const float4*)(x2oa + (size_t)n * H2);
  const float4* c4 = (const float4*)(x2oaa + (size_t)n * H2);
  const float4* v4 = (const float4*)v;
  float r0 = 0.f, r1 = 0.f, r2 = 0.f;
#pragma unroll
  for (int j = 0; j < H2 / 4; ++j) {
    float va[4], vb[4], vc[4], vv[4];
    *(float4*)va = a4[j]; *(float4*)vb = b4[j]; *(float4*)vc = c4[j]; *(float4*)vv = v4[j];
#pragma unroll
    for (int t = 0; t < 4; ++t) {
      r0 = fmaf(va[t], vv[t], r0);
      r1 = fmaf(vb[t], vv[t], r1);
      r2 = fmaf(vc[t], vv[t], r2);
    }
  }
  float bb = db[0];
  ros[n * 2] = r0 + bb;  ros[n * 2 + 1] = r1 + bb;
  rosa[n * 2] = r0 + bb; rosa[n * 2 + 1] = r2 + bb;
}

// ===================== classifier =====================
__global__ __launch_bounds__(128) void k_cls(
    const int* __restrict__ idx, const float* __restrict__ x1o, const float* __restrict__ x2o,
    const float* __restrict__ attt, const float* __restrict__ cw, const float* __restrict__ cb,
    float* __restrict__ lg) {
  int b = blockIdx.x;
  int r = threadIdx.x;
  if (r >= RR) return;
  int i1 = idx[b], i2 = idx[BQ + b];
  float a0 = attt[0], a1 = attt[1];
  float acc = cb[r];
  const float4* q1 = (const float4*)(x1o + (size_t)i1 * H1);
  const float4* q2 = (const float4*)(x2o + (size_t)i1 * H2);
  const float4* q3 = (const float4*)(x1o + (size_t)i2 * H1);
  const float4* q4 = (const float4*)(x2o + (size_t)i2 * H2);
#pragma unroll
  for (int j = 0; j < H1 / 4; ++j) {
    float v[4]; *(float4*)v = q1[j];
#pragma unroll
    for (int t = 0; t < 4; ++t) acc = fmaf(a0 * v[t], cw[(4 * j + t) * RR + r], acc);
  }
#pragma unroll
  for (int j = 0; j < H2 / 4; ++j) {
    float v[4]; *(float4*)v = q2[j];
#pragma unroll
    for (int t = 0; t < 4; ++t) acc = fmaf(a1 * v[t], cw[(H1 + 4 * j + t) * RR + r], acc);
  }
#pragma unroll
  for (int j = 0; j < H1 / 4; ++j) {
    float v[4]; *(float4*)v = q3[j];
#pragma unroll
    for (int t = 0; t < 4; ++t) acc = fmaf(a0 * v[t], cw[(96 + 4 * j + t) * RR + r], acc);
  }
#pragma unroll
  for (int j = 0; j < H2 / 4; ++j) {
    float v[4]; *(float4*)v = q4[j];
#pragma unroll
    for (int t = 0; t < 4; ++t) acc = fmaf(a1 * v[t], cw[(96 + H1 + 4 * j + t) * RR + r], acc);
  }
  lg[(size_t)b * RR + r] = acc;
}

// ===================== launch =====================
extern "C" void kernel_launch(void* const* d_in, const int* in_sizes, int n_in,
                              void* d_out, int out_size, void* d_ws, size_t ws_size,
                              hipStream_t stream) {
  const float* x_o  = (const float*)d_in[0];
  const float* x_a  = (const float*)d_in[1];
  const int*   ei   = (const int*)d_in[2];
  const int*   etA  = (const int*)d_in[3];
  const int*   etB  = (const int*)d_in[4];
  const int*   idx  = (const int*)d_in[5];
  const float* W1   = (const float*)d_in[6];
  const float* rt1  = (const float*)d_in[7];
  const float* b1   = (const float*)d_in[8];
  const float* W2   = (const float*)d_in[9];
  const float* rt2  = (const float*)d_in[10];
  const float* b2   = (const float*)d_in[11];
  const float* attt = (const float*)d_in[12];
  const float* dw   = (const float*)d_in[13];
  const float* db   = (const float*)d_in[14];
  const float* cw   = (const float*)d_in[15];
  const float* cb   = (const float*)d_in[16];

  const size_t NRp = 1300224;
  int* wsI  = (int*)d_ws;
  int* cntA = wsI;                              // NRp -> float inv
  int* cntB = wsI + NRp;                        // NRp -> float inv
  int* sm   = wsI + 2 * NRp;                    // 1024
  int* ordA = sm + 1024;                        // NE
  int* ordB = ordA + NE;                        // NE
  int2*  sdA = (int2*)(ordB + NE);              // NE int2
  float* ivA = (float*)(sdA + NE);              // NE
  int2*  sdB = (int2*)(ivA + NE);               // NE int2
  float* ivB = (float*)(sdB + NE);              // NE
  float* x1o   = ivB + NE;                      // NN*H1 (x1o,x1a,x1aa contiguous for relu)
  float* x1a   = x1o + (size_t)NN * H1;
  float* x1aa  = x1a + (size_t)NN * H1;
  float* x2oa  = x1aa + (size_t)NN * H1;        // NN*H2
  float* x2oaa = x2oa + (size_t)NN * H2;        // NN*H2
  float* smF   = (float*)sm;
  float* hacc  = smF + SM_HACC;
  float* vbuf  = smF + SM_V;

  float* outF   = (float*)d_out;
  float* o_log  = outF;
  float* o_ros  = outF + (size_t)BQ * RR;
  float* o_rosa = o_ros + (size_t)NN * 2;
  float* o_x2o  = o_rosa + (size_t)NN * 2;

  hipMemsetAsync(wsI, 0, (2 * NRp + 1024) * sizeof(int), stream);

  k_hist<<<(NE + 255) / 256, 256, 0, stream>>>(ei, etA, etB, cntA, cntB, sm);
  k_prefix<<<1, 128, 0, stream>>>(sm);
  k_scatter<<<(NE + 255) / 256, 256, 0, stream>>>(etA, etB, sm, ordA, ordB);
  k_inv<<<(NR + 255) / 256, 256, 0, stream>>>(cntA, cntB);
  k_emeta<<<(NE + 255) / 256, 256, 0, stream>>>(ei, ordA, ordB,
                                                (const float*)cntA, (const float*)cntB,
                                                etA, etB, sdA, ivA, sdB, ivB);

  k_root1<<<(NN * H1) / 256, 256, 0, stream>>>(x_o, x_a, rt1, b1, x1o, x1aa, x1a);
  k_edge1<2, 4><<<RR * CPB1, 256, 0, stream>>>(sdA, ivA, sm, SM_START_A, SM_HIST_A,
                                               W1, x_o, x_a, x1o, x1a);
  k_edge1<1, 8><<<RR * CPB1, 256, 0, stream>>>(sdB, ivB, sm, SM_START_B, SM_HIST_B,
                                               W1, x_o, nullptr, x1aa, nullptr);
  k_relu4<<<(3 * NN * H1 / 4 + 255) / 256, 256, 0, stream>>>((float4*)x1o, 3 * NN * H1 / 4);

  k_root2<<<(NN * H2 + 255) / 256, 256, 0, stream>>>(x1o, rt2, b2, o_x2o);
  k_root2<<<(NN * H2 + 255) / 256, 256, 0, stream>>>(x1a, rt2, b2, x2oa);
  k_root2<<<(NN * H2 + 255) / 256, 256, 0, stream>>>(x1aa, rt2, b2, x2oaa);
  k_edge2<2, 4><<<RR * CPB2, 256, 0, stream>>>(sdA, ivA, sm, SM_START_A, SM_HIST_A,
                                               W2, x1o, x1a, o_x2o, x2oa);
  k_edge2<1, 8><<<RR * CPB2, 256, 0, stream>>>(sdB, ivB, sm, SM_START_B, SM_HIST_B,
                                               W2, x1aa, nullptr, x2oaa, nullptr);

  k_colsum<<<128, 256, 0, stream>>>(o_x2o, hacc);
  k_disc<<<1, 64, 0, stream>>>(hacc, dw, vbuf);
  k_ret<<<(NN + 255) / 256, 256, 0, stream>>>(o_x2o, x2oa, x2oaa, vbuf, db, o_ros, o_rosa);
  k_cls<<<BQ, 128, 0, stream>>>(idx, x1o, o_x2o, attt, cw, cb, o_log);
}